// Round 6
// baseline (701.588 us; speedup 1.0000x reference)
//
#include <hip/hip_runtime.h>
#include <stdint.h>

#define BB 2
#define SS 2048
#define DMODEL 512
#define NH 8
#define DHD 64

typedef __attribute__((ext_vector_type(8))) short bf16x8;
typedef __attribute__((ext_vector_type(4))) short s16x4;
typedef __attribute__((ext_vector_type(4))) float fx4;

__device__ __forceinline__ short f2bf(float f) {
    union { float f; uint32_t u; } c; c.f = f;
    uint32_t u = c.u;
    u += 0x7fffu + ((u >> 16) & 1u);   // RNE
    return (short)(u >> 16);
}
__device__ __forceinline__ float bf2f(short s) {
    union { uint32_t u; float f; } c; c.u = ((uint32_t)(uint16_t)s) << 16;
    return c.f;
}

// ---------------------------------------------------------------------------
// Weight fusion: Wqa[d][h] = sum_n Wq[d][n]*Wab[n][h] (h<8: Wa, h>=8: Wb),
// cab[h] = sum_n bq[n]*Wab[n][h] + bias[h].
// ---------------------------------------------------------------------------
__global__ __launch_bounds__(256) void wab_fuse_k(
    const float* __restrict__ Wq, const float* __restrict__ bq,
    const float* __restrict__ Wa, const float* __restrict__ ba,
    const float* __restrict__ Wb, const float* __restrict__ bbias,
    float* __restrict__ Wqa, float* __restrict__ cab)
{
    const int idx = blockIdx.x * 256 + threadIdx.x;   // 8192 outputs
    const int d = idx >> 4, h = idx & 15;
    const float* Wab = (h < 8) ? Wa : Wb;
    const int hh = h & 7;
    float acc = 0.f;
    for (int n = 0; n < DMODEL; ++n)
        acc += Wq[(size_t)d * DMODEL + n] * Wab[n * 8 + hh];
    Wqa[d * 16 + h] = acc;
    if (blockIdx.x == 0 && threadIdx.x < 16) {
        const int h2 = threadIdx.x;
        const float* Wab2 = (h2 < 8) ? Wa : Wb;
        const float* bias2 = (h2 < 8) ? ba : bbias;
        const int hh2 = h2 & 7;
        float c = 0.f;
        for (int n = 0; n < DMODEL; ++n)
            c += bq[n] * Wab2[n * 8 + hh2];
        cab[h2] = c + bias2[hh2];
    }
}

// ---------------------------------------------------------------------------
// Fused QKV + a/b projection. z = blockIdx.z:
//   z=0: q@Wq->qp (bf16 row-major)   z=1: k@Wk->kp   z=2: v@Wv->vT (transposed)
//   z=3: a/b head projection from q with fused weights Wqa/cab.
// ---------------------------------------------------------------------------
__global__ __launch_bounds__(256, 4) void qkv_gemm_k(
    const float* __restrict__ q, const float* __restrict__ k, const float* __restrict__ v,
    const float* __restrict__ Wq, const float* __restrict__ bq,
    const float* __restrict__ Wk, const float* __restrict__ bk,
    const float* __restrict__ Wv, const float* __restrict__ bv,
    const float* __restrict__ Wqa, const float* __restrict__ cab,
    short* __restrict__ qp, short* __restrict__ kp, short* __restrict__ vT,
    float* __restrict__ a_ws, float* __restrict__ b_ws)
{
    __shared__ char smem_raw[512 * 17 * 4];   // 34816 B; GEMM path uses 10240 B
    const int tid = threadIdx.x;
    const int w = tid >> 6, lane = tid & 63;
    const int z = blockIdx.z;

    if (z == 3) {
        float* WqaS = (float*)smem_raw;       // [512][17] padded
        for (int i = tid; i < 8192; i += 256) {
            int kr = i >> 4, h = i & 15;
            WqaS[kr * 17 + h] = Wqa[i];
        }
        __syncthreads();
        const int lin = blockIdx.x * 8 + blockIdx.y;   // [0,512)
#pragma unroll
        for (int rr = 0; rr < 2; ++rr) {
            const int r = lin * 8 + w * 2 + rr;
            const int b = r >> 11, srow = r & (SS - 1);
            float qv[8];
#pragma unroll
            for (int kk = 0; kk < 8; ++kk)
                qv[kk] = q[(size_t)r * DMODEL + kk * 64 + lane];   // coalesced
            float acc[16] = {};
#pragma unroll
            for (int kk = 0; kk < 8; ++kk) {
                const float* wrow = &WqaS[(kk * 64 + lane) * 17];
#pragma unroll
                for (int h = 0; h < 16; ++h)
                    acc[h] += qv[kk] * wrow[h];
            }
#pragma unroll
            for (int h = 0; h < 16; ++h)
#pragma unroll
                for (int off = 1; off < 64; off <<= 1)
                    acc[h] += __shfl_xor(acc[h], off);
            if (lane == 0) {
#pragma unroll
                for (int h = 0; h < 8; ++h) {
                    a_ws[(b * NH + h) * SS + srow] = acc[h] + cab[h];
                    b_ws[(b * NH + h) * SS + srow] = acc[8 + h] + cab[8 + h];
                }
            }
        }
        return;
    }

    short* As = (short*)smem_raw;              // [64][40]
    short* Bs = (short*)(smem_raw + 64 * 40 * 2);
    const float* Af   = (z == 0) ? q  : (z == 1) ? k  : v;
    const float* W    = (z == 0) ? Wq : (z == 1) ? Wk : Wv;
    const float* bias = (z == 0) ? bq : (z == 1) ? bk : bv;
    short* Cp         = (z == 0) ? qp : (z == 1) ? kp : vT;

    const int cl = lane & 15, quad = lane >> 4;
    const int mi = w >> 1, ni = w & 1;
    const int m0 = blockIdx.x * 64, n0 = blockIdx.y * 64;
    fx4 acc[2][2] = {};

    for (int k0 = 0; k0 < DMODEL; k0 += 32) {
        // stage A tile 64x32
#pragma unroll
        for (int it = 0; it < 2; ++it) {
            int idx = tid + it * 256;
            int row = idx >> 3, kq = (idx & 7) * 4;
            const float4 vv = *(const float4*)&Af[(size_t)(m0 + row) * DMODEL + k0 + kq];
            s16x4 sv;
            sv.x = f2bf(vv.x); sv.y = f2bf(vv.y); sv.z = f2bf(vv.z); sv.w = f2bf(vv.w);
            *(s16x4*)&As[row * 40 + kq] = sv;
        }
        // stage W tile 32x64 transposed -> Bs[n][k]
#pragma unroll
        for (int it = 0; it < 2; ++it) {
            int idx = tid + it * 256;
            int kk = idx >> 4, nq = (idx & 15) * 4;
            const float4 vv = *(const float4*)&W[(size_t)(k0 + kk) * DMODEL + n0 + nq];
            Bs[(nq + 0) * 40 + kk] = f2bf(vv.x);
            Bs[(nq + 1) * 40 + kk] = f2bf(vv.y);
            Bs[(nq + 2) * 40 + kk] = f2bf(vv.z);
            Bs[(nq + 3) * 40 + kk] = f2bf(vv.w);
        }
        __syncthreads();
        bf16x8 af[2], bfr[2];
#pragma unroll
        for (int i = 0; i < 2; ++i)
            af[i] = *(const bf16x8*)&As[(mi * 32 + i * 16 + cl) * 40 + quad * 8];
#pragma unroll
        for (int j = 0; j < 2; ++j)
            bfr[j] = *(const bf16x8*)&Bs[(ni * 32 + j * 16 + cl) * 40 + quad * 8];
#pragma unroll
        for (int i = 0; i < 2; ++i)
#pragma unroll
            for (int j = 0; j < 2; ++j)
                acc[i][j] = __builtin_amdgcn_mfma_f32_16x16x32_bf16(af[i], bfr[j], acc[i][j], 0, 0, 0);
        __syncthreads();
    }
    // epilogue: C/D layout col=lane&15, row=quad*4+reg
#pragma unroll
    for (int i = 0; i < 2; ++i) {
#pragma unroll
        for (int j = 0; j < 2; ++j) {
            int col = n0 + ni * 32 + j * 16 + cl;
            float bv = bias[col];
            if (z == 2) {
                // transposed bf16: 4 consecutive s rows pack into one s16x4
                int row0 = m0 + mi * 32 + i * 16 + quad * 4;
                int bb_ = row0 >> 11, sr = row0 & (SS - 1);
                s16x4 o;
                o.x = f2bf(acc[i][j][0] + bv);
                o.y = f2bf(acc[i][j][1] + bv);
                o.z = f2bf(acc[i][j][2] + bv);
                o.w = f2bf(acc[i][j][3] + bv);
                *(s16x4*)&Cp[((size_t)(bb_ * DMODEL + col)) * SS + sr] = o;
            } else {
#pragma unroll
                for (int r = 0; r < 4; ++r) {
                    int row = m0 + mi * 32 + i * 16 + quad * 4 + r;
                    Cp[(size_t)row * DMODEL + col] = f2bf(acc[i][j][r] + bv);
                }
            }
        }
    }
}

// ---------------------------------------------------------------------------
// Final projection: out = ao(bf16) @ Wo + bo, f32 row-major output.
// ---------------------------------------------------------------------------
__global__ __launch_bounds__(256, 4) void out_gemm_k(
    const short* __restrict__ Ab, const float* __restrict__ W,
    const float* __restrict__ bias, float* __restrict__ Cp)
{
    __shared__ short As[64 * 40];
    __shared__ short Bs[64 * 40];
    const int tid = threadIdx.x;
    const int w = tid >> 6, lane = tid & 63;
    const int cl = lane & 15, quad = lane >> 4;
    const int mi = w >> 1, ni = w & 1;
    const int m0 = blockIdx.x * 64, n0 = blockIdx.y * 64;
    fx4 acc[2][2] = {};

    for (int k0 = 0; k0 < DMODEL; k0 += 32) {
#pragma unroll
        for (int it = 0; it < 2; ++it) {
            int idx = tid + it * 256;
            int row = idx >> 3, kq = (idx & 7) * 4;
            *(s16x4*)&As[row * 40 + kq] =
                *(const s16x4*)&Ab[(size_t)(m0 + row) * DMODEL + k0 + kq];
        }
#pragma unroll
        for (int it = 0; it < 2; ++it) {
            int idx = tid + it * 256;
            int kk = idx >> 4, nq = (idx & 15) * 4;
            const float4 vv = *(const float4*)&W[(size_t)(k0 + kk) * DMODEL + n0 + nq];
            Bs[(nq + 0) * 40 + kk] = f2bf(vv.x);
            Bs[(nq + 1) * 40 + kk] = f2bf(vv.y);
            Bs[(nq + 2) * 40 + kk] = f2bf(vv.z);
            Bs[(nq + 3) * 40 + kk] = f2bf(vv.w);
        }
        __syncthreads();
        bf16x8 af[2], bfr[2];
#pragma unroll
        for (int i = 0; i < 2; ++i)
            af[i] = *(const bf16x8*)&As[(mi * 32 + i * 16 + cl) * 40 + quad * 8];
#pragma unroll
        for (int j = 0; j < 2; ++j)
            bfr[j] = *(const bf16x8*)&Bs[(ni * 32 + j * 16 + cl) * 40 + quad * 8];
#pragma unroll
        for (int i = 0; i < 2; ++i)
#pragma unroll
            for (int j = 0; j < 2; ++j)
                acc[i][j] = __builtin_amdgcn_mfma_f32_16x16x32_bf16(af[i], bfr[j], acc[i][j], 0, 0, 0);
        __syncthreads();
    }
#pragma unroll
    for (int i = 0; i < 2; ++i)
#pragma unroll
        for (int j = 0; j < 2; ++j) {
            int col = n0 + ni * 32 + j * 16 + cl;
            float bv = bias[col];
#pragma unroll
            for (int r = 0; r < 4; ++r) {
                int row = m0 + mi * 32 + i * 16 + quad * 4 + r;
                Cp[(size_t)row * DMODEL + col] = acc[i][j][r] + bv;
            }
        }
}

// ---------------------------------------------------------------------------
// Attention, two-pass recompute (no score storage, no max pass).
// Softmax shift-invariance + bounded logits (|s| <~ 40 unmasked; masked =
// -1.44e9 -> exp2 underflows to 0 exactly) make exp2-without-max safe in f32
// (sum < 2048*2^35 << f32 max).  Pass 1: s -> exp2 -> row-sum only (4 live
// f32/lane).  Pass 2: recompute s (QK MFMA 3.4%-utilized; xdiff/K re-reads
// L2-hot), normalize, write attn, PV.  Kills the 64-reg score array that
// spilled ~80 MB each way in rounds 2-4 (FETCH/WRITE excess symmetric).
// ---------------------------------------------------------------------------
__global__ __launch_bounds__(512) void attn_k(
    const short* __restrict__ qp, const short* __restrict__ kp, const short* __restrict__ vT,
    const float* __restrict__ a_ws, const float* __restrict__ b_ws,
    const float* __restrict__ xdiff, const int* __restrict__ mask,
    float* __restrict__ attn, short* __restrict__ ao)
{
    __shared__ char smem[32768];          // psw: 8 waves x 16x72 bf16 (18.4KB); reused as ored (32KB)
    __shared__ float reds[128];

    const int tid = threadIdx.x;
    const int w = tid >> 6, lane = tid & 63;
    const int cl = lane & 15, quad = lane >> 4;

    // XCD-grouped swizzle: 8 h's sharing one xdiff panel run consecutively on
    // the same XCD's L2 (FETCH 176->97 MB measured round 2).
    const int wg = blockIdx.x;
    const int sp = wg >> 3, xcd = wg & 7;
    const int h = sp & 7;
    const int bqt = xcd * 32 + (sp >> 3);
    const int b = bqt >> 7, qt = bqt & 127;
    const int q0 = qt * 16;
    const int bS = b * SS;

    const float LOG2E = 1.44269504f;

    // Q A-frags direct from global (row = cl, k = kc*32+quad*8)
    bf16x8 qf[2];
#pragma unroll
    for (int kc = 0; kc < 2; ++kc)
        qf[kc] = *(const bf16x8*)&qp[(size_t)(bS + q0 + cl) * DMODEL + h * DHD + kc * 32 + quad * 8];

    float ra[4], rb[4];
#pragma unroll
    for (int r = 0; r < 4; ++r) {
        int qi = q0 + quad * 4 + r;
        ra[r] = a_ws[(b * NH + h) * SS + qi] * LOG2E;
        rb[r] = b_ws[(b * NH + h) * SS + qi] * LOG2E;
    }

    const int j0w = w * 256;

    // ---- pass 1: row sums (scores recomputed later, never stored) ----
    float rsum[4] = {};
#pragma unroll
    for (int t = 0; t < 4; ++t) {
        const int j0 = j0w + t * 64;
        fx4 qk[4] = {};
        __builtin_amdgcn_s_setprio(1);
#pragma unroll
        for (int nb = 0; nb < 4; ++nb)
#pragma unroll
            for (int kc = 0; kc < 2; ++kc) {
                bf16x8 kf = *(const bf16x8*)&kp[(size_t)(bS + j0 + nb * 16 + cl) * DMODEL + h * DHD + kc * 32 + quad * 8];
                qk[nb] = __builtin_amdgcn_mfma_f32_16x16x32_bf16(qf[kc], kf, qk[nb], 0, 0, 0);
            }
        __builtin_amdgcn_s_setprio(0);
#pragma unroll
        for (int nb = 0; nb < 4; ++nb) {
            const int j = j0 + nb * 16 + cl;
            const float mv = -1.442695e9f * (float)mask[bS + j];
#pragma unroll
            for (int r = 0; r < 4; ++r) {
                const int qi = q0 + quad * 4 + r;
                const float xd = xdiff[(size_t)(bS + qi) * SS + j];
                float sv = qk[nb][r] * 0.18033688f + mv + ra[r] * xd + rb[r] * (xd * xd);
                rsum[r] += exp2f(sv);
            }
        }
    }
#pragma unroll
    for (int off = 1; off < 16; off <<= 1)
#pragma unroll
        for (int r = 0; r < 4; ++r)
            rsum[r] += __shfl_xor(rsum[r], off);
    if (cl == 0)
#pragma unroll
        for (int r = 0; r < 4; ++r) reds[w * 16 + quad * 4 + r] = rsum[r];
    __syncthreads();
    float gs[4];
#pragma unroll
    for (int r = 0; r < 4; ++r) {
        int i = quad * 4 + r;
        float t0 = reds[i]      + reds[16 + i] + reds[32 + i] + reds[48 + i];
        float t1 = reds[64 + i] + reds[80 + i] + reds[96 + i] + reds[112 + i];
        gs[r] = 1.0f / (t0 + t1);
    }

    // ---- pass 2: recompute scores, normalize, write attn, PV ----
    fx4 oacc[4] = {};
    float* attn_bh = attn + (size_t)(b * NH + h) * SS * SS;
    short* psw = (short*)smem + w * (16 * 72);
    const size_t vbase = (size_t)((b * NH + h) * DHD) * SS;
#pragma unroll
    for (int t = 0; t < 4; ++t) {
        const int j0 = j0w + t * 64;
        fx4 qk[4] = {};
        __builtin_amdgcn_s_setprio(1);
#pragma unroll
        for (int nb = 0; nb < 4; ++nb)
#pragma unroll
            for (int kc = 0; kc < 2; ++kc) {
                bf16x8 kf = *(const bf16x8*)&kp[(size_t)(bS + j0 + nb * 16 + cl) * DMODEL + h * DHD + kc * 32 + quad * 8];
                qk[nb] = __builtin_amdgcn_mfma_f32_16x16x32_bf16(qf[kc], kf, qk[nb], 0, 0, 0);
            }
        __builtin_amdgcn_s_setprio(0);
#pragma unroll
        for (int nb = 0; nb < 4; ++nb) {
            const int j = j0 + nb * 16 + cl;
            const float mv = -1.442695e9f * (float)mask[bS + j];
#pragma unroll
            for (int r = 0; r < 4; ++r) {
                const int qi = q0 + quad * 4 + r;
                const float xd = xdiff[(size_t)(bS + qi) * SS + j];
                float sv = qk[nb][r] * 0.18033688f + mv + ra[r] * xd + rb[r] * (xd * xd);
                float p = exp2f(sv) * gs[r];
                __builtin_nontemporal_store(p, &attn_bh[(size_t)(q0 + quad * 4 + r) * SS + j]);
                psw[(quad * 4 + r) * 72 + nb * 16 + cl] = f2bf(p);
            }
        }
        bf16x8 pf[2];
#pragma unroll
        for (int kc = 0; kc < 2; ++kc)
            pf[kc] = *(const bf16x8*)&psw[cl * 72 + kc * 32 + quad * 8];
        __builtin_amdgcn_s_setprio(1);
#pragma unroll
        for (int nb = 0; nb < 4; ++nb)
#pragma unroll
            for (int kc = 0; kc < 2; ++kc) {
                bf16x8 vf = *(const bf16x8*)&vT[vbase + (size_t)(nb * 16 + cl) * SS + j0 + kc * 32 + quad * 8];
                oacc[nb] = __builtin_amdgcn_mfma_f32_16x16x32_bf16(pf[kc], vf, oacc[nb], 0, 0, 0);
            }
        __builtin_amdgcn_s_setprio(0);
    }

    // ---- cross-wave output reduction (smem reused as fp32 scratch) ----
    __syncthreads();
    float* ored = (float*)smem;
#pragma unroll
    for (int nb = 0; nb < 4; ++nb)
#pragma unroll
        for (int r = 0; r < 4; ++r)
            ored[w * 1024 + (quad * 4 + r) * 64 + nb * 16 + cl] = oacc[nb][r];
    __syncthreads();
    if (tid < 256) {
        int i = tid >> 4, dq = (tid & 15) * 4;
        float sx = 0, sy = 0, sz = 0, sw = 0;
#pragma unroll
        for (int ww = 0; ww < 8; ++ww) {
            const float4 vv = *(const float4*)&ored[ww * 1024 + i * 64 + dq];
            sx += vv.x; sy += vv.y; sz += vv.z; sw += vv.w;
        }
        s16x4 o;
        o.x = f2bf(sx); o.y = f2bf(sy); o.z = f2bf(sz); o.w = f2bf(sw);
        *(s16x4*)&ao[(size_t)(bS + q0 + i) * DMODEL + h * DHD + dq] = o;
    }
}

// ---------------------------------------------------------------------------
extern "C" void kernel_launch(void* const* d_in, const int* in_sizes, int n_in,
                              void* d_out, int out_size, void* d_ws, size_t ws_size,
                              hipStream_t stream)
{
    (void)in_sizes; (void)n_in; (void)out_size; (void)ws_size;
    const float* q     = (const float*)d_in[0];
    const float* k     = (const float*)d_in[1];
    const float* v     = (const float*)d_in[2];
    const float* xdiff = (const float*)d_in[3];
    const int*   mask  = (const int*)d_in[4];
    const float* Wq = (const float*)d_in[5];
    const float* bq = (const float*)d_in[6];
    const float* Wk = (const float*)d_in[7];
    const float* bk = (const float*)d_in[8];
    const float* Wv = (const float*)d_in[9];
    const float* bv = (const float*)d_in[10];
    const float* Wa = (const float*)d_in[11];
    const float* ba = (const float*)d_in[12];
    const float* Wb = (const float*)d_in[13];
    const float* bb = (const float*)d_in[14];
    const float* Wo = (const float*)d_in[15];
    const float* bo = (const float*)d_in[16];

    char* ws = (char*)d_ws;
    short* qp   = (short*)(ws + 0);          // 4096x512 bf16
    short* kp   = (short*)(ws + 4194304);
    short* vT   = (short*)(ws + 8388608);    // (B,H,DH,S) bf16
    float* a_ws = (float*)(ws + 12582912);   // (B,H,S) f32
    float* b_ws = (float*)(ws + 12713984);
    short* ao   = (short*)(ws + 12845056);   // 4096x512 bf16 (attn output pre-Wo)
    float* Wqa  = (float*)(ws + 17039360);   // 512x16 f32 fused a/b weights
    float* cab  = (float*)(ws + 17072128);   // 16 f32

    float* out  = (float*)d_out;
    float* attn = out + (size_t)BB * SS * DMODEL;

    hipLaunchKernelGGL(wab_fuse_k, dim3(32), dim3(256), 0, stream,
                       Wq, bq, Wa, ba, Wb, bb, Wqa, cab);
    hipLaunchKernelGGL(qkv_gemm_k, dim3(64, 8, 4), dim3(256), 0, stream,
                       q, k, v, Wq, bq, Wk, bk, Wv, bv, Wqa, cab, qp, kp, vT, a_ws, b_ws);
    hipLaunchKernelGGL(attn_k, dim3(2048), dim3(512), 0, stream,
                       qp, kp, vT, a_ws, b_ws, xdiff, mask, attn, ao);
    hipLaunchKernelGGL(out_gemm_k, dim3(64, 8), dim3(256), 0, stream, ao, Wo, bo, out);
}

// Round 7
// 556.170 us; speedup vs baseline: 1.2615x; 1.2615x over previous
//
#include <hip/hip_runtime.h>
#include <stdint.h>

#define BB 2
#define SS 2048
#define DMODEL 512
#define NH 8
#define DHD 64

typedef __attribute__((ext_vector_type(8))) short bf16x8;
typedef __attribute__((ext_vector_type(4))) short s16x4;
typedef __attribute__((ext_vector_type(4))) float fx4;

__device__ __forceinline__ short f2bf(float f) {
    union { float f; uint32_t u; } c; c.f = f;
    uint32_t u = c.u;
    u += 0x7fffu + ((u >> 16) & 1u);   // RNE
    return (short)(u >> 16);
}
__device__ __forceinline__ float bf2f(short s) {
    union { uint32_t u; float f; } c; c.u = ((uint32_t)(uint16_t)s) << 16;
    return c.f;
}

// ---------------------------------------------------------------------------
// Weight fusion: Wqa[d][h] = sum_n Wq[d][n]*Wab[n][h] (h<8: Wa, h>=8: Wb),
// cab[h] = sum_n bq[n]*Wab[n][h] + bias[h].
// One wave per output (8192 Wqa + 16 cab = 8208 waves, 2052 blocks) —
// the old 32-block serial version was latency-bound.
// ---------------------------------------------------------------------------
__global__ __launch_bounds__(256) void wab_fuse_k(
    const float* __restrict__ Wq, const float* __restrict__ bq,
    const float* __restrict__ Wa, const float* __restrict__ ba,
    const float* __restrict__ Wb, const float* __restrict__ bbias,
    float* __restrict__ Wqa, float* __restrict__ cab)
{
    const int wid = (blockIdx.x * 256 + threadIdx.x) >> 6;
    const int lane = threadIdx.x & 63;
    if (wid < 8192) {
        const int d = wid >> 4, h = wid & 15;
        const float* Wab = (h < 8) ? Wa : Wb;
        const int hh = h & 7;
        float acc = 0.f;
#pragma unroll
        for (int i = 0; i < 8; ++i) {
            int n = lane * 8 + i;
            acc += Wq[(size_t)d * DMODEL + n] * Wab[n * 8 + hh];
        }
#pragma unroll
        for (int off = 1; off < 64; off <<= 1)
            acc += __shfl_xor(acc, off);
        if (lane == 0) Wqa[d * 16 + h] = acc;
    } else if (wid < 8208) {
        const int h2 = wid - 8192;
        const float* Wab2 = (h2 < 8) ? Wa : Wb;
        const float* bias2 = (h2 < 8) ? ba : bbias;
        const int hh2 = h2 & 7;
        float c = 0.f;
#pragma unroll
        for (int i = 0; i < 8; ++i) {
            int n = lane * 8 + i;
            c += bq[n] * Wab2[n * 8 + hh2];
        }
#pragma unroll
        for (int off = 1; off < 64; off <<= 1)
            c += __shfl_xor(c, off);
        if (lane == 0) cab[h2] = c + bias2[hh2];
    }
}

// ---------------------------------------------------------------------------
// Fused QKV + a/b projection. z = blockIdx.z:
//   z=0: q@Wq->qp (bf16 row-major)   z=1: k@Wk->kp   z=2: v@Wv->vT (transposed)
//   z=3: a/b head projection from q with fused weights Wqa/cab.
// ---------------------------------------------------------------------------
__global__ __launch_bounds__(256, 4) void qkv_gemm_k(
    const float* __restrict__ q, const float* __restrict__ k, const float* __restrict__ v,
    const float* __restrict__ Wq, const float* __restrict__ bq,
    const float* __restrict__ Wk, const float* __restrict__ bk,
    const float* __restrict__ Wv, const float* __restrict__ bv,
    const float* __restrict__ Wqa, const float* __restrict__ cab,
    short* __restrict__ qp, short* __restrict__ kp, short* __restrict__ vT,
    float* __restrict__ a_ws, float* __restrict__ b_ws)
{
    __shared__ char smem_raw[512 * 17 * 4];   // 34816 B; GEMM path uses 10240 B
    const int tid = threadIdx.x;
    const int w = tid >> 6, lane = tid & 63;
    const int z = blockIdx.z;

    if (z == 3) {
        float* WqaS = (float*)smem_raw;       // [512][17] padded
        for (int i = tid; i < 8192; i += 256) {
            int kr = i >> 4, h = i & 15;
            WqaS[kr * 17 + h] = Wqa[i];
        }
        __syncthreads();
        const int lin = blockIdx.x * 8 + blockIdx.y;   // [0,512)
#pragma unroll
        for (int rr = 0; rr < 2; ++rr) {
            const int r = lin * 8 + w * 2 + rr;
            const int b = r >> 11, srow = r & (SS - 1);
            float qv[8];
#pragma unroll
            for (int kk = 0; kk < 8; ++kk)
                qv[kk] = q[(size_t)r * DMODEL + kk * 64 + lane];   // coalesced
            float acc[16] = {};
#pragma unroll
            for (int kk = 0; kk < 8; ++kk) {
                const float* wrow = &WqaS[(kk * 64 + lane) * 17];
#pragma unroll
                for (int h = 0; h < 16; ++h)
                    acc[h] += qv[kk] * wrow[h];
            }
#pragma unroll
            for (int h = 0; h < 16; ++h)
#pragma unroll
                for (int off = 1; off < 64; off <<= 1)
                    acc[h] += __shfl_xor(acc[h], off);
            if (lane == 0) {
#pragma unroll
                for (int h = 0; h < 8; ++h) {
                    a_ws[(b * NH + h) * SS + srow] = acc[h] + cab[h];
                    b_ws[(b * NH + h) * SS + srow] = acc[8 + h] + cab[8 + h];
                }
            }
        }
        return;
    }

    short* As = (short*)smem_raw;              // [64][40]
    short* Bs = (short*)(smem_raw + 64 * 40 * 2);
    const float* Af   = (z == 0) ? q  : (z == 1) ? k  : v;
    const float* W    = (z == 0) ? Wq : (z == 1) ? Wk : Wv;
    const float* bias = (z == 0) ? bq : (z == 1) ? bk : bv;
    short* Cp         = (z == 0) ? qp : (z == 1) ? kp : vT;

    const int cl = lane & 15, quad = lane >> 4;
    const int mi = w >> 1, ni = w & 1;
    const int m0 = blockIdx.x * 64, n0 = blockIdx.y * 64;
    fx4 acc[2][2] = {};

    for (int k0 = 0; k0 < DMODEL; k0 += 32) {
        // stage A tile 64x32
#pragma unroll
        for (int it = 0; it < 2; ++it) {
            int idx = tid + it * 256;
            int row = idx >> 3, kq = (idx & 7) * 4;
            const float4 vv = *(const float4*)&Af[(size_t)(m0 + row) * DMODEL + k0 + kq];
            s16x4 sv;
            sv.x = f2bf(vv.x); sv.y = f2bf(vv.y); sv.z = f2bf(vv.z); sv.w = f2bf(vv.w);
            *(s16x4*)&As[row * 40 + kq] = sv;
        }
        // stage W tile 32x64 transposed -> Bs[n][k]
#pragma unroll
        for (int it = 0; it < 2; ++it) {
            int idx = tid + it * 256;
            int kk = idx >> 4, nq = (idx & 15) * 4;
            const float4 vv = *(const float4*)&W[(size_t)(k0 + kk) * DMODEL + n0 + nq];
            Bs[(nq + 0) * 40 + kk] = f2bf(vv.x);
            Bs[(nq + 1) * 40 + kk] = f2bf(vv.y);
            Bs[(nq + 2) * 40 + kk] = f2bf(vv.z);
            Bs[(nq + 3) * 40 + kk] = f2bf(vv.w);
        }
        __syncthreads();
        bf16x8 af[2], bfr[2];
#pragma unroll
        for (int i = 0; i < 2; ++i)
            af[i] = *(const bf16x8*)&As[(mi * 32 + i * 16 + cl) * 40 + quad * 8];
#pragma unroll
        for (int j = 0; j < 2; ++j)
            bfr[j] = *(const bf16x8*)&Bs[(ni * 32 + j * 16 + cl) * 40 + quad * 8];
#pragma unroll
        for (int i = 0; i < 2; ++i)
#pragma unroll
            for (int j = 0; j < 2; ++j)
                acc[i][j] = __builtin_amdgcn_mfma_f32_16x16x32_bf16(af[i], bfr[j], acc[i][j], 0, 0, 0);
        __syncthreads();
    }
    // epilogue: C/D layout col=lane&15, row=quad*4+reg
#pragma unroll
    for (int i = 0; i < 2; ++i) {
#pragma unroll
        for (int j = 0; j < 2; ++j) {
            int col = n0 + ni * 32 + j * 16 + cl;
            float bv = bias[col];
            if (z == 2) {
                // transposed bf16: 4 consecutive s rows pack into one s16x4
                int row0 = m0 + mi * 32 + i * 16 + quad * 4;
                int bb_ = row0 >> 11, sr = row0 & (SS - 1);
                s16x4 o;
                o.x = f2bf(acc[i][j][0] + bv);
                o.y = f2bf(acc[i][j][1] + bv);
                o.z = f2bf(acc[i][j][2] + bv);
                o.w = f2bf(acc[i][j][3] + bv);
                *(s16x4*)&Cp[((size_t)(bb_ * DMODEL + col)) * SS + sr] = o;
            } else {
#pragma unroll
                for (int r = 0; r < 4; ++r) {
                    int row = m0 + mi * 32 + i * 16 + quad * 4 + r;
                    Cp[(size_t)row * DMODEL + col] = f2bf(acc[i][j][r] + bv);
                }
            }
        }
    }
}

// ---------------------------------------------------------------------------
// Final projection: out = ao(bf16) @ Wo + bo, f32 row-major output.
// ---------------------------------------------------------------------------
__global__ __launch_bounds__(256, 4) void out_gemm_k(
    const short* __restrict__ Ab, const float* __restrict__ W,
    const float* __restrict__ bias, float* __restrict__ Cp)
{
    __shared__ short As[64 * 40];
    __shared__ short Bs[64 * 40];
    const int tid = threadIdx.x;
    const int w = tid >> 6, lane = tid & 63;
    const int cl = lane & 15, quad = lane >> 4;
    const int mi = w >> 1, ni = w & 1;
    const int m0 = blockIdx.x * 64, n0 = blockIdx.y * 64;
    fx4 acc[2][2] = {};

    for (int k0 = 0; k0 < DMODEL; k0 += 32) {
#pragma unroll
        for (int it = 0; it < 2; ++it) {
            int idx = tid + it * 256;
            int row = idx >> 3, kq = (idx & 7) * 4;
            *(s16x4*)&As[row * 40 + kq] =
                *(const s16x4*)&Ab[(size_t)(m0 + row) * DMODEL + k0 + kq];
        }
#pragma unroll
        for (int it = 0; it < 2; ++it) {
            int idx = tid + it * 256;
            int kk = idx >> 4, nq = (idx & 15) * 4;
            const float4 vv = *(const float4*)&W[(size_t)(k0 + kk) * DMODEL + n0 + nq];
            Bs[(nq + 0) * 40 + kk] = f2bf(vv.x);
            Bs[(nq + 1) * 40 + kk] = f2bf(vv.y);
            Bs[(nq + 2) * 40 + kk] = f2bf(vv.z);
            Bs[(nq + 3) * 40 + kk] = f2bf(vv.w);
        }
        __syncthreads();
        bf16x8 af[2], bfr[2];
#pragma unroll
        for (int i = 0; i < 2; ++i)
            af[i] = *(const bf16x8*)&As[(mi * 32 + i * 16 + cl) * 40 + quad * 8];
#pragma unroll
        for (int j = 0; j < 2; ++j)
            bfr[j] = *(const bf16x8*)&Bs[(ni * 32 + j * 16 + cl) * 40 + quad * 8];
#pragma unroll
        for (int i = 0; i < 2; ++i)
#pragma unroll
            for (int j = 0; j < 2; ++j)
                acc[i][j] = __builtin_amdgcn_mfma_f32_16x16x32_bf16(af[i], bfr[j], acc[i][j], 0, 0, 0);
        __syncthreads();
    }
#pragma unroll
    for (int i = 0; i < 2; ++i)
#pragma unroll
        for (int j = 0; j < 2; ++j) {
            int col = n0 + ni * 32 + j * 16 + cl;
            float bv = bias[col];
#pragma unroll
            for (int r = 0; r < 4; ++r) {
                int row = m0 + mi * 32 + i * 16 + quad * 4 + r;
                Cp[(size_t)row * DMODEL + col] = acc[i][j][r] + bv;
            }
        }
}

// ---------------------------------------------------------------------------
// Attention, single pass over K with PACKED-BF16 score storage.
// No max pass (exp2-no-max safe: bounded unmasked logits; masked underflows
// to 0).  exp2 values are positive with f32 exponent range -> bf16 (same
// 8-bit exponent) stores them exactly enough (rel err 2^-9).  64 scores/lane
// = 32 packed u32 regs, vs 64 f32 regs that spilled in r2-r4 and a recompute
// pass that doubled HBM traffic in r6 (FETCH 150->309 MB: K/xdiff re-reads
// are NOT L2-hot).  Plain attn stores (NT removed: r0 evidence WRITE 267 MB
// ideal without NT; +79..220 MB with NT).
// ---------------------------------------------------------------------------
__global__ __launch_bounds__(512) void attn_k(
    const short* __restrict__ qp, const short* __restrict__ kp, const short* __restrict__ vT,
    const float* __restrict__ a_ws, const float* __restrict__ b_ws,
    const float* __restrict__ xdiff, const int* __restrict__ mask,
    float* __restrict__ attn, short* __restrict__ ao)
{
    __shared__ char smem[32768];          // psw: 8 waves x 16x72 bf16 (18.4KB); reused as ored (32KB)
    __shared__ float reds[128];

    const int tid = threadIdx.x;
    const int w = tid >> 6, lane = tid & 63;
    const int cl = lane & 15, quad = lane >> 4;

    // XCD-grouped swizzle: 8 h's sharing one xdiff panel run consecutively on
    // the same XCD's L2 (FETCH 176->97 MB measured round 2).
    const int wg = blockIdx.x;
    const int sp = wg >> 3, xcd = wg & 7;
    const int h = sp & 7;
    const int bqt = xcd * 32 + (sp >> 3);
    const int b = bqt >> 7, qt = bqt & 127;
    const int q0 = qt * 16;
    const int bS = b * SS;

    const float LOG2E = 1.44269504f;

    // Q A-frags direct from global (row = cl, k = kc*32+quad*8)
    bf16x8 qf[2];
#pragma unroll
    for (int kc = 0; kc < 2; ++kc)
        qf[kc] = *(const bf16x8*)&qp[(size_t)(bS + q0 + cl) * DMODEL + h * DHD + kc * 32 + quad * 8];

    float ra[4], rb[4];
#pragma unroll
    for (int r = 0; r < 4; ++r) {
        int qi = q0 + quad * 4 + r;
        ra[r] = a_ws[(b * NH + h) * SS + qi] * LOG2E;
        rb[r] = b_ws[(b * NH + h) * SS + qi] * LOG2E;
    }

    const int j0w = w * 256;

    // ---- phase 1: QK^T -> exp2 -> rsum; store e packed bf16 (32 regs) ----
    uint32_t es[4][8];
    float rsum[4] = {};
#pragma unroll
    for (int t = 0; t < 4; ++t) {
        const int j0 = j0w + t * 64;
        fx4 qk[4] = {};
        __builtin_amdgcn_s_setprio(1);
#pragma unroll
        for (int nb = 0; nb < 4; ++nb)
#pragma unroll
            for (int kc = 0; kc < 2; ++kc) {
                bf16x8 kf = *(const bf16x8*)&kp[(size_t)(bS + j0 + nb * 16 + cl) * DMODEL + h * DHD + kc * 32 + quad * 8];
                qk[nb] = __builtin_amdgcn_mfma_f32_16x16x32_bf16(qf[kc], kf, qk[nb], 0, 0, 0);
            }
        __builtin_amdgcn_s_setprio(0);
#pragma unroll
        for (int nb = 0; nb < 4; ++nb) {
            const int j = j0 + nb * 16 + cl;
            const float mv = -1.442695e9f * (float)mask[bS + j];
            float e4[4];
#pragma unroll
            for (int r = 0; r < 4; ++r) {
                const int qi = q0 + quad * 4 + r;
                const float xd = xdiff[(size_t)(bS + qi) * SS + j];
                float sv = qk[nb][r] * 0.18033688f + mv + ra[r] * xd + rb[r] * (xd * xd);
                e4[r] = exp2f(sv);
                rsum[r] += e4[r];
            }
            es[t][nb * 2 + 0] = (uint32_t)(uint16_t)f2bf(e4[0]) | ((uint32_t)(uint16_t)f2bf(e4[1]) << 16);
            es[t][nb * 2 + 1] = (uint32_t)(uint16_t)f2bf(e4[2]) | ((uint32_t)(uint16_t)f2bf(e4[3]) << 16);
        }
    }
#pragma unroll
    for (int off = 1; off < 16; off <<= 1)
#pragma unroll
        for (int r = 0; r < 4; ++r)
            rsum[r] += __shfl_xor(rsum[r], off);
    if (cl == 0)
#pragma unroll
        for (int r = 0; r < 4; ++r) reds[w * 16 + quad * 4 + r] = rsum[r];
    __syncthreads();
    float gs[4];
#pragma unroll
    for (int r = 0; r < 4; ++r) {
        int i = quad * 4 + r;
        float t0 = reds[i]      + reds[16 + i] + reds[32 + i] + reds[48 + i];
        float t1 = reds[64 + i] + reds[80 + i] + reds[96 + i] + reds[112 + i];
        gs[r] = 1.0f / (t0 + t1);
    }

    // ---- phase 2: unpack, normalize, write attn (plain), PV ----
    fx4 oacc[4] = {};
    float* attn_bh = attn + (size_t)(b * NH + h) * SS * SS;
    short* psw = (short*)smem + w * (16 * 72);
    const size_t vbase = (size_t)((b * NH + h) * DHD) * SS;
#pragma unroll
    for (int t = 0; t < 4; ++t) {
        const int j0 = j0w + t * 64;
#pragma unroll
        for (int nb = 0; nb < 4; ++nb) {
            const int j = j0 + nb * 16 + cl;
            const uint32_t p01 = es[t][nb * 2 + 0];
            const uint32_t p23 = es[t][nb * 2 + 1];
            float e4[4];
            e4[0] = bf2f((short)(p01 & 0xffff));
            e4[1] = bf2f((short)(p01 >> 16));
            e4[2] = bf2f((short)(p23 & 0xffff));
            e4[3] = bf2f((short)(p23 >> 16));
#pragma unroll
            for (int r = 0; r < 4; ++r) {
                float p = e4[r] * gs[r];
                attn_bh[(size_t)(q0 + quad * 4 + r) * SS + j] = p;
                psw[(quad * 4 + r) * 72 + nb * 16 + cl] = f2bf(p);
            }
        }
        bf16x8 pf[2];
#pragma unroll
        for (int kc = 0; kc < 2; ++kc)
            pf[kc] = *(const bf16x8*)&psw[cl * 72 + kc * 32 + quad * 8];
        __builtin_amdgcn_s_setprio(1);
#pragma unroll
        for (int nb = 0; nb < 4; ++nb)
#pragma unroll
            for (int kc = 0; kc < 2; ++kc) {
                bf16x8 vf = *(const bf16x8*)&vT[vbase + (size_t)(nb * 16 + cl) * SS + j0 + kc * 32 + quad * 8];
                oacc[nb] = __builtin_amdgcn_mfma_f32_16x16x32_bf16(pf[kc], vf, oacc[nb], 0, 0, 0);
            }
        __builtin_amdgcn_s_setprio(0);
    }

    // ---- cross-wave output reduction (smem reused as fp32 scratch) ----
    __syncthreads();
    float* ored = (float*)smem;
#pragma unroll
    for (int nb = 0; nb < 4; ++nb)
#pragma unroll
        for (int r = 0; r < 4; ++r)
            ored[w * 1024 + (quad * 4 + r) * 64 + nb * 16 + cl] = oacc[nb][r];
    __syncthreads();
    if (tid < 256) {
        int i = tid >> 4, dq = (tid & 15) * 4;
        float sx = 0, sy = 0, sz = 0, sw = 0;
#pragma unroll
        for (int ww = 0; ww < 8; ++ww) {
            const float4 vv = *(const float4*)&ored[ww * 1024 + i * 64 + dq];
            sx += vv.x; sy += vv.y; sz += vv.z; sw += vv.w;
        }
        s16x4 o;
        o.x = f2bf(sx); o.y = f2bf(sy); o.z = f2bf(sz); o.w = f2bf(sw);
        *(s16x4*)&ao[(size_t)(bS + q0 + i) * DMODEL + h * DHD + dq] = o;
    }
}

// ---------------------------------------------------------------------------
extern "C" void kernel_launch(void* const* d_in, const int* in_sizes, int n_in,
                              void* d_out, int out_size, void* d_ws, size_t ws_size,
                              hipStream_t stream)
{
    (void)in_sizes; (void)n_in; (void)out_size; (void)ws_size;
    const float* q     = (const float*)d_in[0];
    const float* k     = (const float*)d_in[1];
    const float* v     = (const float*)d_in[2];
    const float* xdiff = (const float*)d_in[3];
    const int*   mask  = (const int*)d_in[4];
    const float* Wq = (const float*)d_in[5];
    const float* bq = (const float*)d_in[6];
    const float* Wk = (const float*)d_in[7];
    const float* bk = (const float*)d_in[8];
    const float* Wv = (const float*)d_in[9];
    const float* bv = (const float*)d_in[10];
    const float* Wa = (const float*)d_in[11];
    const float* ba = (const float*)d_in[12];
    const float* Wb = (const float*)d_in[13];
    const float* bb = (const float*)d_in[14];
    const float* Wo = (const float*)d_in[15];
    const float* bo = (const float*)d_in[16];

    char* ws = (char*)d_ws;
    short* qp   = (short*)(ws + 0);          // 4096x512 bf16
    short* kp   = (short*)(ws + 4194304);
    short* vT   = (short*)(ws + 8388608);    // (B,H,DH,S) bf16
    float* a_ws = (float*)(ws + 12582912);   // (B,H,S) f32
    float* b_ws = (float*)(ws + 12713984);
    short* ao   = (short*)(ws + 12845056);   // 4096x512 bf16 (attn output pre-Wo)
    float* Wqa  = (float*)(ws + 17039360);   // 512x16 f32 fused a/b weights
    float* cab  = (float*)(ws + 17072128);   // 16 f32

    float* out  = (float*)d_out;
    float* attn = out + (size_t)BB * SS * DMODEL;

    hipLaunchKernelGGL(wab_fuse_k, dim3(2052), dim3(256), 0, stream,
                       Wq, bq, Wa, ba, Wb, bb, Wqa, cab);
    hipLaunchKernelGGL(qkv_gemm_k, dim3(64, 8, 4), dim3(256), 0, stream,
                       q, k, v, Wq, bq, Wk, bk, Wv, bv, Wqa, cab, qp, kp, vT, a_ws, b_ws);
    hipLaunchKernelGGL(attn_k, dim3(2048), dim3(512), 0, stream,
                       qp, kp, vT, a_ws, b_ws, xdiff, mask, attn, ao);
    hipLaunchKernelGGL(out_gemm_k, dim3(64, 8), dim3(256), 0, stream, ao, Wo, bo, out);
}